// Round 8
// baseline (340.405 us; speedup 1.0000x reference)
//
#include <hip/hip_runtime.h>
#include <hip/hip_bf16.h>

// Symmetric contraction (MACE-style), B=2048, C=256, I=9, E=10. fp32 only
// (fp32 absmax 0.5 vs threshold 7.24; bf16/MFMA numerically dead).
//
// Round-8: occupancy fix via INTRA-BLOCK m-split, LDS <= 32 KB.
// Occupancy model fitted to r2/r3/r4/r7: LDS allocated in ~32KB granules from
// a ~128KB pool -> 36.9KB xs cost 64KB -> only 2 blocks/CU all along.
// Now: both waves of a block share ONE xs tile (same 8 b x 64 c):
//   wave0 -> triples [0,110); wave1 -> triples [110,165) + pairs + singles
//   wave0 acc -> LDS, barrier, wave1 adds + stores. No partial buf/combine.
// LDS = 18.4 (xs) + 8.2 (red) = 26.6KB -> 4 blocks/CU = 2 waves/SIMD.
// Inner loop = r4's validated body, unchanged (r5 lesson). No atomics (r6).
// No waves/EU launch-bounds cap (r2).

#define NB 2048
#define NC 256
#define NI 9
#define NE 10

#define N_TRI 165
#define N_PAIR 45
#define BT 8

// T layout (float4): T3 [165][10][256] | T2 [45][10][256] | T1 [9][10][256]
#define T3N (N_TRI * NE * NC)
#define T2N (N_PAIR * NE * NC)
#define T1N (NI * NE * NC)

#define MSPLIT 110   // m=110 decodes to (3,3,4); 110 rows / 109 row-units

// ---------------- prep: Sym (LDS) x W -> T, e-loop inside ----------------
__global__ __launch_bounds__(256) void sc_prep(
    const float* __restrict__ U1_s, const float* __restrict__ U2_s,
    const float* __restrict__ U3_s, const float* __restrict__ U1_v,
    const float* __restrict__ U2_v, const float* __restrict__ U3_v,
    const float* __restrict__ W1_s, const float* __restrict__ W2_s,
    const float* __restrict__ W3_s, const float* __restrict__ W1_v,
    const float* __restrict__ W2_v, const float* __restrict__ W3_v,
    float* __restrict__ ws)
{
    const int m = blockIdx.x;    // 0..218
    const int tid = threadIdx.x; // 0..255
    float4* __restrict__ T3 = (float4*)ws;
    float4* __restrict__ T2 = T3 + T3N;
    float4* __restrict__ T1 = T2 + T2N;

    __shared__ float sym[128];

    if (m < N_TRI) {
        if (tid < 113) {
            int ii = 0, jj = 0, kk = 0, cnt = 0;
            for (int i = 0; i < NI; i++)
                for (int j = i; j < NI; j++)
                    for (int k = j; k < NI; k++) {
                        if (cnt == m) { ii = i; jj = j; kk = k; }
                        cnt++;
                    }
            int P[6][3]; int np;
            if (ii == jj && jj == kk) {
                np = 1;
                P[0][0] = ii; P[0][1] = ii; P[0][2] = ii;
            } else if (ii == jj) {
                np = 3;
                P[0][0] = ii; P[0][1] = ii; P[0][2] = kk;
                P[1][0] = ii; P[1][1] = kk; P[1][2] = ii;
                P[2][0] = kk; P[2][1] = ii; P[2][2] = ii;
            } else if (jj == kk) {
                np = 3;
                P[0][0] = ii; P[0][1] = jj; P[0][2] = jj;
                P[1][0] = jj; P[1][1] = ii; P[1][2] = jj;
                P[2][0] = jj; P[2][1] = jj; P[2][2] = ii;
            } else {
                np = 6;
                P[0][0] = ii; P[0][1] = jj; P[0][2] = kk;
                P[1][0] = ii; P[1][1] = kk; P[1][2] = jj;
                P[2][0] = jj; P[2][1] = ii; P[2][2] = kk;
                P[3][0] = jj; P[3][1] = kk; P[3][2] = ii;
                P[4][0] = kk; P[4][1] = ii; P[4][2] = jj;
                P[5][0] = kk; P[5][1] = jj; P[5][2] = ii;
            }
            float s = 0.f;
            if (tid < 23) {
                for (int p = 0; p < np; p++)
                    s += U3_s[((P[p][0] * NI + P[p][1]) * NI + P[p][2]) * 23 + tid];
            } else {
                int a = (tid - 23) / 30, t = (tid - 23) % 30;
                for (int p = 0; p < np; p++)
                    s += U3_v[(((a * NI + P[p][0]) * NI + P[p][1]) * NI + P[p][2]) * 30 + t];
            }
            sym[tid] = s;
        }
        __syncthreads();
        const int c = tid;
        for (int e = 0; e < NE; e++) {
            float s = 0.f, v0 = 0.f, v1 = 0.f, v2 = 0.f;
            #pragma unroll
            for (int t = 0; t < 23; t++)
                s = fmaf(sym[t], W3_s[(e * 23 + t) * NC + c], s);
            #pragma unroll
            for (int t = 0; t < 30; t++) {
                float wv = W3_v[(e * 30 + t) * NC + c];
                v0 = fmaf(sym[23 + t], wv, v0);
                v1 = fmaf(sym[53 + t], wv, v1);
                v2 = fmaf(sym[83 + t], wv, v2);
            }
            T3[(m * NE + e) * NC + c] = make_float4(s, v0, v1, v2);
        }
    } else if (m < N_TRI + N_PAIR) {
        const int mm = m - N_TRI;
        if (tid < 15) {
            int ii = 0, jj = 0, cnt = 0;
            for (int i = 0; i < NI; i++)
                for (int j = i; j < NI; j++) {
                    if (cnt == mm) { ii = i; jj = j; }
                    cnt++;
                }
            float s;
            if (tid < 3) {
                s = U2_s[(ii * NI + jj) * 3 + tid];
                if (ii != jj) s += U2_s[(jj * NI + ii) * 3 + tid];
            } else {
                int a = (tid - 3) / 4, t = (tid - 3) % 4;
                s = U2_v[((a * NI + ii) * NI + jj) * 4 + t];
                if (ii != jj) s += U2_v[((a * NI + jj) * NI + ii) * 4 + t];
            }
            sym[tid] = s;
        }
        __syncthreads();
        const int c = tid;
        for (int e = 0; e < NE; e++) {
            float s = 0.f, v0 = 0.f, v1 = 0.f, v2 = 0.f;
            #pragma unroll
            for (int t = 0; t < 3; t++)
                s = fmaf(sym[t], W2_s[(e * 3 + t) * NC + c], s);
            #pragma unroll
            for (int t = 0; t < 4; t++) {
                float wv = W2_v[(e * 4 + t) * NC + c];
                v0 = fmaf(sym[3 + t],  wv, v0);
                v1 = fmaf(sym[7 + t],  wv, v1);
                v2 = fmaf(sym[11 + t], wv, v2);
            }
            T2[(mm * NE + e) * NC + c] = make_float4(s, v0, v1, v2);
        }
    } else {
        const int i = m - N_TRI - N_PAIR;
        const int c = tid;
        for (int e = 0; e < NE; e++) {
            float w1s = W1_s[e * NC + c], w1v = W1_v[e * NC + c];
            T1[(i * NE + e) * NC + c] = make_float4(
                U1_s[i] * w1s,
                U1_v[0 * NI + i] * w1v,
                U1_v[1 * NI + i] * w1v,
                U1_v[2 * NI + i] * w1v);
        }
    }
}

// ---------------- main ----------------
__device__ __forceinline__ void tri_advance(int& i, int& j, int& k) {
    k++;
    if (k == NI) { j++; if (j == NI) { i++; j = i; } k = j; }
}

#define ROW_FMA(BUF)                                              \
    {                                                             \
        _Pragma("unroll")                                         \
        for (int e = 0; e < NE; e++) {                            \
            const float4 t = BUF[e];                              \
            _Pragma("unroll")                                     \
            for (int n = 0; n < BT; n++) {                        \
                const float p = w[e][n] * phi[n];                 \
                acc[n][0] = fmaf(p, t.x, acc[n][0]);              \
                acc[n][1] = fmaf(p, t.y, acc[n][1]);              \
                acc[n][2] = fmaf(p, t.z, acc[n][2]);              \
                acc[n][3] = fmaf(p, t.w, acc[n][3]);              \
            }                                                     \
        }                                                         \
    }

template <int M0, int M1, int I0, int J0, int K0>
__device__ __forceinline__ void do_triples(
    const float4* __restrict__ T3, int c, const float* __restrict__ xb,
    const float (&w)[NE][BT], float (&acc)[BT][4])
{
    float4 bufA[NE], bufB[NE];
    #pragma unroll
    for (int e = 0; e < NE; e++) bufA[e] = T3[(M0 * NE + e) * NC + c];
    int i = I0, j = J0, k = K0;
    for (int m = M0; m + 1 < M1; m += 2) {
        #pragma unroll
        for (int e = 0; e < NE; e++) bufB[e] = T3[((m + 1) * NE + e) * NC + c];
        {
            float phi[BT];
            #pragma unroll
            for (int n = 0; n < BT; n++)
                phi[n] = xb[(i * BT + n) * 64] * xb[(j * BT + n) * 64]
                       * xb[(k * BT + n) * 64];
            ROW_FMA(bufA)
        }
        tri_advance(i, j, k);
        const int mp = (m + 2 < M1) ? m + 2 : M1 - 1;
        #pragma unroll
        for (int e = 0; e < NE; e++) bufA[e] = T3[(mp * NE + e) * NC + c];
        {
            float phi[BT];
            #pragma unroll
            for (int n = 0; n < BT; n++)
                phi[n] = xb[(i * BT + n) * 64] * xb[(j * BT + n) * 64]
                       * xb[(k * BT + n) * 64];
            ROW_FMA(bufB)
        }
        tri_advance(i, j, k);
    }
    if ((M1 - M0) & 1) {
        float phi[BT];
        #pragma unroll
        for (int n = 0; n < BT; n++)
            phi[n] = xb[(i * BT + n) * 64] * xb[(j * BT + n) * 64]
                   * xb[(k * BT + n) * 64];
        ROW_FMA(bufA)
    }
}

// grid 1024 x 128 threads (2 waves). One block = one (8b x 64c) tile.
// wave0: triples [0,110) -> acc to LDS. wave1: rest -> adds + stores.
__global__ __launch_bounds__(128) void sc_main(
    const float* __restrict__ x, const float* __restrict__ y,
    const float* __restrict__ ws, float* __restrict__ out)
{
    const int tid = threadIdx.x;
    const int tx  = tid & 63;
    const int wv  = __builtin_amdgcn_readfirstlane(tid >> 6);  // 0 or 1, uniform
    const int bid = blockIdx.x;
    const int xcd    = bid & 7;
    const int c_tile = xcd >> 1;               // XCD pair owns one c-slice of T
    const int b_tile = ((bid >> 3) << 1) | (xcd & 1);   // 0..255
    const int c0 = c_tile << 6;
    const int c  = c0 + tx;
    const int b0 = b_tile << 3;                // 8 b's per block, shared by waves

    __shared__ float xs[NI][BT][64];    // 18.4 KB, shared by both waves
    __shared__ float red[BT][4][64];    //  8.2 KB, wave0 partials

    // cooperative staging: 512 (n,cc) pairs over 128 threads
    #pragma unroll
    for (int p = 0; p < 4; p++) {
        const int pair = tid + p * 128;
        const int n = pair >> 6, cc = pair & 63;
        const float* xp = x + ((size_t)(b0 + n) * NC + c0 + cc) * NI;
        #pragma unroll
        for (int i = 0; i < NI; i++) xs[i][n][cc] = xp[i];
    }
    __syncthreads();
    const float* xb = &xs[0][0][tx];    // xb[(i*BT+n)*64]

    // y weights: uniform (same b0 for both waves) -> s_load
    float w[NE][BT];
    #pragma unroll
    for (int n = 0; n < BT; n++)
        #pragma unroll
        for (int e = 0; e < NE; e++) w[e][n] = y[(b0 + n) * NE + e];

    float acc[BT][4];
    #pragma unroll
    for (int n = 0; n < BT; n++)
        #pragma unroll
        for (int h = 0; h < 4; h++) acc[n][h] = 0.f;

    const float4* __restrict__ T3 = (const float4*)ws;
    const float4* __restrict__ T2 = T3 + T3N;
    const float4* __restrict__ T1 = T2 + T2N;

    if (wv == 0) {
        do_triples<0, MSPLIT, 0, 0, 0>(T3, c, xb, w, acc);
    } else {
        do_triples<MSPLIT, N_TRI, 3, 3, 4>(T3, c, xb, w, acc);

        // pairs: 45 rows, unroll-2 A/B
        {
            float4 bufA[NE], bufB[NE];
            #pragma unroll
            for (int e = 0; e < NE; e++) bufA[e] = T2[e * NC + c];
            int i = 0, j = 0;
            for (int m = 0; m + 1 < N_PAIR; m += 2) {
                #pragma unroll
                for (int e = 0; e < NE; e++) bufB[e] = T2[((m + 1) * NE + e) * NC + c];
                {
                    float phi[BT];
                    #pragma unroll
                    for (int n = 0; n < BT; n++)
                        phi[n] = xb[(i * BT + n) * 64] * xb[(j * BT + n) * 64];
                    ROW_FMA(bufA)
                }
                j++; if (j == NI) { i++; j = i; }
                const int mp = (m + 2 < N_PAIR) ? m + 2 : N_PAIR - 1;
                #pragma unroll
                for (int e = 0; e < NE; e++) bufA[e] = T2[(mp * NE + e) * NC + c];
                {
                    float phi[BT];
                    #pragma unroll
                    for (int n = 0; n < BT; n++)
                        phi[n] = xb[(i * BT + n) * 64] * xb[(j * BT + n) * 64];
                    ROW_FMA(bufB)
                }
                j++; if (j == NI) { i++; j = i; }
            }
            {   // tail row 44 in bufA
                float phi[BT];
                #pragma unroll
                for (int n = 0; n < BT; n++)
                    phi[n] = xb[(i * BT + n) * 64] * xb[(j * BT + n) * 64];
                ROW_FMA(bufA)
            }
        }

        // singles
        for (int i = 0; i < NI; i++) {
            float4 tc[NE];
            #pragma unroll
            for (int e = 0; e < NE; e++) tc[e] = T1[(i * NE + e) * NC + c];
            float phi[BT];
            #pragma unroll
            for (int n = 0; n < BT; n++) phi[n] = xb[(i * BT + n) * 64];
            ROW_FMA(tc)
        }
    }

    // intra-block combine: wave0 -> LDS, barrier, wave1 adds + stores.
    if (wv == 0) {
        #pragma unroll
        for (int n = 0; n < BT; n++)
            #pragma unroll
            for (int h = 0; h < 4; h++) red[n][h][tx] = acc[n][h];
    }
    __syncthreads();
    if (wv == 1) {
        #pragma unroll
        for (int n = 0; n < BT; n++) {
            float* ob = out + (size_t)(b0 + n) * (4 * NC);
            ob[c]              = acc[n][0] + red[n][0][tx];
            ob[NC + 3 * c + 0] = acc[n][1] + red[n][1][tx];
            ob[NC + 3 * c + 1] = acc[n][2] + red[n][2][tx];
            ob[NC + 3 * c + 2] = acc[n][3] + red[n][3][tx];
        }
    }
}

extern "C" void kernel_launch(void* const* d_in, const int* in_sizes, int n_in,
                              void* d_out, int out_size, void* d_ws, size_t ws_size,
                              hipStream_t stream) {
    const float* x    = (const float*)d_in[0];
    const float* y    = (const float*)d_in[1];
    const float* U1_s = (const float*)d_in[2];
    const float* U2_s = (const float*)d_in[3];
    const float* U3_s = (const float*)d_in[4];
    const float* U1_v = (const float*)d_in[5];
    const float* U2_v = (const float*)d_in[6];
    const float* U3_v = (const float*)d_in[7];
    const float* W1_s = (const float*)d_in[8];
    const float* W2_s = (const float*)d_in[9];
    const float* W3_s = (const float*)d_in[10];
    const float* W1_v = (const float*)d_in[11];
    const float* W2_v = (const float*)d_in[12];
    const float* W3_v = (const float*)d_in[13];
    float* out = (float*)d_out;
    float* ws  = (float*)d_ws;   // 8.97 MB T table, rebuilt every call

    sc_prep<<<N_TRI + N_PAIR + NI, 256, 0, stream>>>(
        U1_s, U2_s, U3_s, U1_v, U2_v, U3_v,
        W1_s, W2_s, W3_s, W1_v, W2_v, W3_v, ws);
    sc_main<<<1024, 128, 0, stream>>>(x, y, ws, out);
}

// Round 9
// 270.947 us; speedup vs baseline: 1.2564x; 1.2564x over previous
//
#include <hip/hip_runtime.h>
#include <hip/hip_bf16.h>

// Symmetric contraction (MACE-style), B=2048, C=256, I=9, E=10. fp32 only
// (fp32 absmax 0.5 vs threshold 7.24; bf16/MFMA numerically dead).
//
// Round-9: 256-THREAD blocks, 4-way intra-block m-split.
// Residency evidence: every 128-thr round (r4/r7/r8) plateaus at ~1.8
// blocks/CU (occupancy ~11%) regardless of LDS (36.9 or 26.6 KB) and grid;
// the only round that packed >2 blocks/CU used 256-thr blocks (r2, 47%).
// One block = one (8b x 64c) tile, 4 waves:
//   wv0: triples [0,55) from (0,0,0)   wv1: triples [55,110) from (1,2,4)
//   wv2: triples [110,165) from (3,3,4) wv3: pairs (45) + singles (9)
// Combine: serial ping-pong via one 8.2 KB LDS buffer (6 barriers).
// LDS = 18.4 (xs, shared) + 8.2 (red) = 26.6 KB.
// Inner loop = r4's validated body, unchanged (r5 lesson). No atomics (r6).
// No waves/EU launch-bounds cap (r2).

#define NB 2048
#define NC 256
#define NI 9
#define NE 10

#define N_TRI 165
#define N_PAIR 45
#define BT 8

// T layout (float4): T3 [165][10][256] | T2 [45][10][256] | T1 [9][10][256]
#define T3N (N_TRI * NE * NC)
#define T2N (N_PAIR * NE * NC)
#define T1N (NI * NE * NC)

// ---------------- prep: Sym (LDS) x W -> T, e-loop inside ----------------
__global__ __launch_bounds__(256) void sc_prep(
    const float* __restrict__ U1_s, const float* __restrict__ U2_s,
    const float* __restrict__ U3_s, const float* __restrict__ U1_v,
    const float* __restrict__ U2_v, const float* __restrict__ U3_v,
    const float* __restrict__ W1_s, const float* __restrict__ W2_s,
    const float* __restrict__ W3_s, const float* __restrict__ W1_v,
    const float* __restrict__ W2_v, const float* __restrict__ W3_v,
    float* __restrict__ ws)
{
    const int m = blockIdx.x;    // 0..218
    const int tid = threadIdx.x; // 0..255
    float4* __restrict__ T3 = (float4*)ws;
    float4* __restrict__ T2 = T3 + T3N;
    float4* __restrict__ T1 = T2 + T2N;

    __shared__ float sym[128];

    if (m < N_TRI) {
        if (tid < 113) {
            int ii = 0, jj = 0, kk = 0, cnt = 0;
            for (int i = 0; i < NI; i++)
                for (int j = i; j < NI; j++)
                    for (int k = j; k < NI; k++) {
                        if (cnt == m) { ii = i; jj = j; kk = k; }
                        cnt++;
                    }
            int P[6][3]; int np;
            if (ii == jj && jj == kk) {
                np = 1;
                P[0][0] = ii; P[0][1] = ii; P[0][2] = ii;
            } else if (ii == jj) {
                np = 3;
                P[0][0] = ii; P[0][1] = ii; P[0][2] = kk;
                P[1][0] = ii; P[1][1] = kk; P[1][2] = ii;
                P[2][0] = kk; P[2][1] = ii; P[2][2] = ii;
            } else if (jj == kk) {
                np = 3;
                P[0][0] = ii; P[0][1] = jj; P[0][2] = jj;
                P[1][0] = jj; P[1][1] = ii; P[1][2] = jj;
                P[2][0] = jj; P[2][1] = jj; P[2][2] = ii;
            } else {
                np = 6;
                P[0][0] = ii; P[0][1] = jj; P[0][2] = kk;
                P[1][0] = ii; P[1][1] = kk; P[1][2] = jj;
                P[2][0] = jj; P[2][1] = ii; P[2][2] = kk;
                P[3][0] = jj; P[3][1] = kk; P[3][2] = ii;
                P[4][0] = kk; P[4][1] = ii; P[4][2] = jj;
                P[5][0] = kk; P[5][1] = jj; P[5][2] = ii;
            }
            float s = 0.f;
            if (tid < 23) {
                for (int p = 0; p < np; p++)
                    s += U3_s[((P[p][0] * NI + P[p][1]) * NI + P[p][2]) * 23 + tid];
            } else {
                int a = (tid - 23) / 30, t = (tid - 23) % 30;
                for (int p = 0; p < np; p++)
                    s += U3_v[(((a * NI + P[p][0]) * NI + P[p][1]) * NI + P[p][2]) * 30 + t];
            }
            sym[tid] = s;
        }
        __syncthreads();
        const int c = tid;
        for (int e = 0; e < NE; e++) {
            float s = 0.f, v0 = 0.f, v1 = 0.f, v2 = 0.f;
            #pragma unroll
            for (int t = 0; t < 23; t++)
                s = fmaf(sym[t], W3_s[(e * 23 + t) * NC + c], s);
            #pragma unroll
            for (int t = 0; t < 30; t++) {
                float wv = W3_v[(e * 30 + t) * NC + c];
                v0 = fmaf(sym[23 + t], wv, v0);
                v1 = fmaf(sym[53 + t], wv, v1);
                v2 = fmaf(sym[83 + t], wv, v2);
            }
            T3[(m * NE + e) * NC + c] = make_float4(s, v0, v1, v2);
        }
    } else if (m < N_TRI + N_PAIR) {
        const int mm = m - N_TRI;
        if (tid < 15) {
            int ii = 0, jj = 0, cnt = 0;
            for (int i = 0; i < NI; i++)
                for (int j = i; j < NI; j++) {
                    if (cnt == mm) { ii = i; jj = j; }
                    cnt++;
                }
            float s;
            if (tid < 3) {
                s = U2_s[(ii * NI + jj) * 3 + tid];
                if (ii != jj) s += U2_s[(jj * NI + ii) * 3 + tid];
            } else {
                int a = (tid - 3) / 4, t = (tid - 3) % 4;
                s = U2_v[((a * NI + ii) * NI + jj) * 4 + t];
                if (ii != jj) s += U2_v[((a * NI + jj) * NI + ii) * 4 + t];
            }
            sym[tid] = s;
        }
        __syncthreads();
        const int c = tid;
        for (int e = 0; e < NE; e++) {
            float s = 0.f, v0 = 0.f, v1 = 0.f, v2 = 0.f;
            #pragma unroll
            for (int t = 0; t < 3; t++)
                s = fmaf(sym[t], W2_s[(e * 3 + t) * NC + c], s);
            #pragma unroll
            for (int t = 0; t < 4; t++) {
                float wv = W2_v[(e * 4 + t) * NC + c];
                v0 = fmaf(sym[3 + t],  wv, v0);
                v1 = fmaf(sym[7 + t],  wv, v1);
                v2 = fmaf(sym[11 + t], wv, v2);
            }
            T2[(mm * NE + e) * NC + c] = make_float4(s, v0, v1, v2);
        }
    } else {
        const int i = m - N_TRI - N_PAIR;
        const int c = tid;
        for (int e = 0; e < NE; e++) {
            float w1s = W1_s[e * NC + c], w1v = W1_v[e * NC + c];
            T1[(i * NE + e) * NC + c] = make_float4(
                U1_s[i] * w1s,
                U1_v[0 * NI + i] * w1v,
                U1_v[1 * NI + i] * w1v,
                U1_v[2 * NI + i] * w1v);
        }
    }
}

// ---------------- main ----------------
__device__ __forceinline__ void tri_advance(int& i, int& j, int& k) {
    k++;
    if (k == NI) { j++; if (j == NI) { i++; j = i; } k = j; }
}

#define ROW_FMA(BUF)                                              \
    {                                                             \
        _Pragma("unroll")                                         \
        for (int e = 0; e < NE; e++) {                            \
            const float4 t = BUF[e];                              \
            _Pragma("unroll")                                     \
            for (int n = 0; n < BT; n++) {                        \
                const float p = w[e][n] * phi[n];                 \
                acc[n][0] = fmaf(p, t.x, acc[n][0]);              \
                acc[n][1] = fmaf(p, t.y, acc[n][1]);              \
                acc[n][2] = fmaf(p, t.z, acc[n][2]);              \
                acc[n][3] = fmaf(p, t.w, acc[n][3]);              \
            }                                                     \
        }                                                         \
    }

template <int M0, int M1, int I0, int J0, int K0>
__device__ __forceinline__ void do_triples(
    const float4* __restrict__ T3, int c, const float* __restrict__ xb,
    const float (&w)[NE][BT], float (&acc)[BT][4])
{
    float4 bufA[NE], bufB[NE];
    #pragma unroll
    for (int e = 0; e < NE; e++) bufA[e] = T3[(M0 * NE + e) * NC + c];
    int i = I0, j = J0, k = K0;
    for (int m = M0; m + 1 < M1; m += 2) {
        #pragma unroll
        for (int e = 0; e < NE; e++) bufB[e] = T3[((m + 1) * NE + e) * NC + c];
        {
            float phi[BT];
            #pragma unroll
            for (int n = 0; n < BT; n++)
                phi[n] = xb[(i * BT + n) * 64] * xb[(j * BT + n) * 64]
                       * xb[(k * BT + n) * 64];
            ROW_FMA(bufA)
        }
        tri_advance(i, j, k);
        const int mp = (m + 2 < M1) ? m + 2 : M1 - 1;
        #pragma unroll
        for (int e = 0; e < NE; e++) bufA[e] = T3[(mp * NE + e) * NC + c];
        {
            float phi[BT];
            #pragma unroll
            for (int n = 0; n < BT; n++)
                phi[n] = xb[(i * BT + n) * 64] * xb[(j * BT + n) * 64]
                       * xb[(k * BT + n) * 64];
            ROW_FMA(bufB)
        }
        tri_advance(i, j, k);
    }
    if ((M1 - M0) & 1) {
        float phi[BT];
        #pragma unroll
        for (int n = 0; n < BT; n++)
            phi[n] = xb[(i * BT + n) * 64] * xb[(j * BT + n) * 64]
                   * xb[(k * BT + n) * 64];
        ROW_FMA(bufA)
    }
}

// grid 1024 x 256 threads (4 waves). One block = one (8b x 64c) tile.
// wv0: tri [0,55)  wv1: tri [55,110)  wv2: tri [110,165)  wv3: pairs+singles.
// Partition starts (compile-time decode): m=55 -> (1,2,4); m=110 -> (3,3,4).
__global__ __launch_bounds__(256) void sc_main(
    const float* __restrict__ x, const float* __restrict__ y,
    const float* __restrict__ ws, float* __restrict__ out)
{
    const int tid = threadIdx.x;
    const int tx  = tid & 63;
    const int wv  = __builtin_amdgcn_readfirstlane(tid >> 6);  // 0..3, uniform
    const int bid = blockIdx.x;
    const int xcd    = bid & 7;
    const int c_tile = xcd >> 1;               // XCD pair owns one c-slice of T
    const int b_tile = ((bid >> 3) << 1) | (xcd & 1);   // 0..255
    const int c0 = c_tile << 6;
    const int c  = c0 + tx;
    const int b0 = b_tile << 3;                // 8 b's per block, shared

    __shared__ float xs[NI][BT][64];    // 18.4 KB, shared by all 4 waves
    __shared__ float red[BT][4][64];    //  8.2 KB ping-pong combine buffer

    // cooperative staging: 512 (n,cc) pairs over 256 threads
    #pragma unroll
    for (int p = 0; p < 2; p++) {
        const int pair = tid + p * 256;
        const int n = pair >> 6, cc = pair & 63;
        const float* xp = x + ((size_t)(b0 + n) * NC + c0 + cc) * NI;
        #pragma unroll
        for (int i = 0; i < NI; i++) xs[i][n][cc] = xp[i];
    }
    __syncthreads();
    const float* xb = &xs[0][0][tx];    // xb[(i*BT+n)*64]

    // y weights: uniform (same b0 for all waves) -> s_load
    float w[NE][BT];
    #pragma unroll
    for (int n = 0; n < BT; n++)
        #pragma unroll
        for (int e = 0; e < NE; e++) w[e][n] = y[(b0 + n) * NE + e];

    float acc[BT][4];
    #pragma unroll
    for (int n = 0; n < BT; n++)
        #pragma unroll
        for (int h = 0; h < 4; h++) acc[n][h] = 0.f;

    const float4* __restrict__ T3 = (const float4*)ws;
    const float4* __restrict__ T2 = T3 + T3N;
    const float4* __restrict__ T1 = T2 + T2N;

    if (wv == 0) {
        do_triples<0, 55, 0, 0, 0>(T3, c, xb, w, acc);
    } else if (wv == 1) {
        do_triples<55, 110, 1, 2, 4>(T3, c, xb, w, acc);
    } else if (wv == 2) {
        do_triples<110, N_TRI, 3, 3, 4>(T3, c, xb, w, acc);
    } else {
        // pairs: 45 rows, unroll-2 A/B
        {
            float4 bufA[NE], bufB[NE];
            #pragma unroll
            for (int e = 0; e < NE; e++) bufA[e] = T2[e * NC + c];
            int i = 0, j = 0;
            for (int m = 0; m + 1 < N_PAIR; m += 2) {
                #pragma unroll
                for (int e = 0; e < NE; e++) bufB[e] = T2[((m + 1) * NE + e) * NC + c];
                {
                    float phi[BT];
                    #pragma unroll
                    for (int n = 0; n < BT; n++)
                        phi[n] = xb[(i * BT + n) * 64] * xb[(j * BT + n) * 64];
                    ROW_FMA(bufA)
                }
                j++; if (j == NI) { i++; j = i; }
                const int mp = (m + 2 < N_PAIR) ? m + 2 : N_PAIR - 1;
                #pragma unroll
                for (int e = 0; e < NE; e++) bufA[e] = T2[(mp * NE + e) * NC + c];
                {
                    float phi[BT];
                    #pragma unroll
                    for (int n = 0; n < BT; n++)
                        phi[n] = xb[(i * BT + n) * 64] * xb[(j * BT + n) * 64];
                    ROW_FMA(bufB)
                }
                j++; if (j == NI) { i++; j = i; }
            }
            {   // tail row 44 in bufA
                float phi[BT];
                #pragma unroll
                for (int n = 0; n < BT; n++)
                    phi[n] = xb[(i * BT + n) * 64] * xb[(j * BT + n) * 64];
                ROW_FMA(bufA)
            }
        }
        // singles
        for (int i = 0; i < NI; i++) {
            float4 tc[NE];
            #pragma unroll
            for (int e = 0; e < NE; e++) tc[e] = T1[(i * NE + e) * NC + c];
            float phi[BT];
            #pragma unroll
            for (int n = 0; n < BT; n++) phi[n] = xb[(i * BT + n) * 64];
            ROW_FMA(tc)
        }
    }

    // serial ping-pong combine: wv0 -> wv1 -> wv2 -> wv3 stores.
    if (wv == 0) {
        #pragma unroll
        for (int n = 0; n < BT; n++)
            #pragma unroll
            for (int h = 0; h < 4; h++) red[n][h][tx] = acc[n][h];
    }
    __syncthreads();
    if (wv == 1) {
        #pragma unroll
        for (int n = 0; n < BT; n++)
            #pragma unroll
            for (int h = 0; h < 4; h++) acc[n][h] += red[n][h][tx];
    }
    __syncthreads();
    if (wv == 1) {
        #pragma unroll
        for (int n = 0; n < BT; n++)
            #pragma unroll
            for (int h = 0; h < 4; h++) red[n][h][tx] = acc[n][h];
    }
    __syncthreads();
    if (wv == 2) {
        #pragma unroll
        for (int n = 0; n < BT; n++)
            #pragma unroll
            for (int h = 0; h < 4; h++) acc[n][h] += red[n][h][tx];
    }
    __syncthreads();
    if (wv == 2) {
        #pragma unroll
        for (int n = 0; n < BT; n++)
            #pragma unroll
            for (int h = 0; h < 4; h++) red[n][h][tx] = acc[n][h];
    }
    __syncthreads();
    if (wv == 3) {
        #pragma unroll
        for (int n = 0; n < BT; n++) {
            float* ob = out + (size_t)(b0 + n) * (4 * NC);
            ob[c]              = acc[n][0] + red[n][0][tx];
            ob[NC + 3 * c + 0] = acc[n][1] + red[n][1][tx];
            ob[NC + 3 * c + 1] = acc[n][2] + red[n][2][tx];
            ob[NC + 3 * c + 2] = acc[n][3] + red[n][3][tx];
        }
    }
}

extern "C" void kernel_launch(void* const* d_in, const int* in_sizes, int n_in,
                              void* d_out, int out_size, void* d_ws, size_t ws_size,
                              hipStream_t stream) {
    const float* x    = (const float*)d_in[0];
    const float* y    = (const float*)d_in[1];
    const float* U1_s = (const float*)d_in[2];
    const float* U2_s = (const float*)d_in[3];
    const float* U3_s = (const float*)d_in[4];
    const float* U1_v = (const float*)d_in[5];
    const float* U2_v = (const float*)d_in[6];
    const float* U3_v = (const float*)d_in[7];
    const float* W1_s = (const float*)d_in[8];
    const float* W2_s = (const float*)d_in[9];
    const float* W3_s = (const float*)d_in[10];
    const float* W1_v = (const float*)d_in[11];
    const float* W2_v = (const float*)d_in[12];
    const float* W3_v = (const float*)d_in[13];
    float* out = (float*)d_out;
    float* ws  = (float*)d_ws;   // 8.97 MB T table, rebuilt every call

    sc_prep<<<N_TRI + N_PAIR + NI, 256, 0, stream>>>(
        U1_s, U2_s, U3_s, U1_v, U2_v, U3_v,
        W1_s, W2_s, W3_s, W1_v, W2_v, W3_v, ws);
    sc_main<<<1024, 256, 0, stream>>>(x, y, ws, out);
}